// Round 17
// baseline (130.825 us; speedup 1.0000x reference)
//
#include <hip/hip_runtime.h>
#include <hip/hip_bf16.h>

#define DEVINL __device__ __forceinline__

typedef __attribute__((ext_vector_type(8))) short short8;
typedef __attribute__((ext_vector_type(4))) float f32x4;
typedef __attribute__((ext_vector_type(2))) unsigned int u32x2;

DEVINL unsigned short f2bf(float x) {
  __hip_bfloat16 h = __float2bfloat16(x);
  return __builtin_bit_cast(unsigned short, h);
}
DEVINL unsigned int pk2(float lo, float hi) {
  return (unsigned int)f2bf(lo) | ((unsigned int)f2bf(hi) << 16);
}
DEVINL float bf2f(unsigned short h) {
  union { unsigned int u; float f; } c; c.u = ((unsigned int)h) << 16;
  return c.f;
}
// tanh-form GELU (branchless): |diff vs erf-GELU| <~3e-3, far under threshold.
DEVINL float gelu_f(float x) {
  const float u = x * x;
  const float y = x * (0.7978845608f + 0.0356774081f * u);
  const float e = __expf(-2.0f * y);
  return x * __builtin_amdgcn_rcpf(1.0f + e);
}
DEVINL f32x4 mfma16(short8 a, short8 b, f32x4 c) {
  return __builtin_amdgcn_mfma_f32_16x16x32_bf16(a, b, c, 0, 0, 0);
}

// GEMM from LDS A-tile (row-major, ldx bf16 elems) with pre-packed B frags.
template<int KSTEPS, int MT, int NT>
DEVINL void gemm_tiles(const unsigned short* Xl, int ldx,
                       const unsigned short* __restrict__ Wp,
                       int lane, int w, f32x4 (&acc)[MT][2])
{
  const int rr = lane & 15;
  const int kg = (lane >> 4) << 3;
  __builtin_amdgcn_s_setprio(1);
  #pragma unroll
  for (int t = 0; t < KSTEPS; ++t) {
    short8 a[MT];
    #pragma unroll
    for (int m = 0; m < MT; ++m)
      a[m] = *(const short8*)(Xl + (m * 16 + rr) * ldx + t * 32 + kg);
    #pragma unroll
    for (int c = 0; c < 2; ++c) {
      short8 bf = *(const short8*)(Wp + ((size_t)(t * NT + (w * 2 + c)) * 64 + lane) * 8);
      #pragma unroll
      for (int m = 0; m < MT; ++m)
        acc[m][c] = mfma16(a[m], bf, acc[m][c]);
    }
  }
  __builtin_amdgcn_s_setprio(0);
}

// ---- pack all weights -> bf16 MFMA B-fragments in ws ------------------------
__global__ __launch_bounds__(256) void k_pack(
    const float* __restrict__ W1w,  const float* __restrict__ W2w,
    const float* __restrict__ W3w,  const float* __restrict__ W11w,
    const float* __restrict__ W12w, const float* __restrict__ W13w,
    const float* __restrict__ Winw, const float* __restrict__ Woutw,
    unsigned short* __restrict__ dst)
{
  const int f = blockIdx.x * 256 + threadIdx.x;
  if (f >= 36864) return;
  const float* src; int row0 = 0, Ncols = 128, NT = 8, lf;
  if (f < 20480) {
    const int seg = f >> 11; lf = f & 2047;
    switch (seg) {
      case 0: src = W1w;  row0 = 0;   break;
      case 1: src = W1w;  row0 = 128; break;
      case 2: src = W1w;  row0 = 256; break;
      case 3: src = W2w;  break;
      case 4: src = W3w;  break;
      case 5: src = W11w; row0 = 0;   break;
      case 6: src = W11w; row0 = 128; break;
      case 7: src = W11w; row0 = 256; break;
      case 8: src = W12w; break;
      default: src = W13w; break;
    }
  } else if (f < 28672) { src = Winw; lf = f - 20480; NT = 32; Ncols = 512; }
  else { src = Woutw; lf = f - 28672; }
  const int l = lf & 63;
  const int g = lf >> 6;
  const int c = g % NT;
  const int t = g / NT;
  const int r0 = row0 + t * 32 + ((l >> 4) << 3);
  const int col = c * 16 + (l & 15);
  short8 vv;
  #pragma unroll
  for (int b = 0; b < 8; ++b)
    vv[b] = (short)f2bf(src[(size_t)(r0 + b) * Ncols + col]);
  *(short8*)(dst + (size_t)f * 8) = vv;
}

// ---- precompute P1 = X@Wtop + bias (f32), P3 = X@Wbot (bf16), X:[4096,128] --
__global__ __launch_bounds__(256) void k_pre(
    const float* __restrict__ X,
    const unsigned short* __restrict__ Wtp,
    const unsigned short* __restrict__ Wbp,
    const float* __restrict__ bias,
    float* __restrict__ P1, unsigned short* __restrict__ P3)
{
  __shared__ __align__(16) unsigned short Xs2[16 * 136];
  const int tid = threadIdx.x;
  const int lane = tid & 63;
  const int w = tid >> 6;
  const int rr = lane & 15;
  const int kg = (lane >> 4) << 3;
  const int row0 = blockIdx.x * 16;

  for (int e = tid; e < 512; e += 256) {
    const int r = e >> 5, q = (e & 31) << 2;
    float4 v = *(const float4*)(X + (size_t)(row0 + r) * 128 + q);
    u32x2 pk; pk[0] = pk2(v.x, v.y); pk[1] = pk2(v.z, v.w);
    *(u32x2*)(&Xs2[r * 136 + q]) = pk;
  }
  __syncthreads();

  const f32x4 zf = {0.f, 0.f, 0.f, 0.f};
  f32x4 a0[2] = {zf, zf}, a1[2] = {zf, zf};
  #pragma unroll
  for (int t = 0; t < 4; ++t) {
    const short8 a = *(const short8*)(&Xs2[rr * 136 + t * 32 + kg]);
    #pragma unroll
    for (int c = 0; c < 2; ++c) {
      short8 bt = *(const short8*)(Wtp + ((size_t)(t * 8 + (w * 2 + c)) * 64 + lane) * 8);
      a0[c] = mfma16(a, bt, a0[c]);
      short8 bb = *(const short8*)(Wbp + ((size_t)(t * 8 + (w * 2 + c)) * 64 + lane) * 8);
      a1[c] = mfma16(a, bb, a1[c]);
    }
  }
  #pragma unroll
  for (int c = 0; c < 2; ++c) {
    const int col = w * 32 + c * 16 + rr;
    const float b = bias[col];
    #pragma unroll
    for (int r = 0; r < 4; ++r) {
      const int row = row0 + ((lane >> 4) << 2) + r;
      P1[(size_t)row * 128 + col] = a0[c][r] + b;
      P3[(size_t)row * 128 + col] = f2bf(a1[c][r]);
    }
  }
}

// ---------------- node message pass + LN1 -> hVn1; side-writes hEb -----------
// GEMM3 collapsed: dh = (sum_k mask[k]*gelu(G2)[k,:]) @ W3 + (sum mask)*b3
// Staging: load-all-then-store-all enforced via asm register pins; hEb
// side-write deferred to after B2 (drains under GEMM2's MFMA).
template<bool HEB>
__global__ __launch_bounds__(256, 4) void k_node_t(
    const float* __restrict__ hV, const float* __restrict__ hE,
    unsigned short* __restrict__ hEbOut,
    const int* __restrict__ Eidx, const float* __restrict__ maskA,
    const float* __restrict__ P1g, const unsigned short* __restrict__ P3g,
    const unsigned short* __restrict__ Wmidp,
    const unsigned short* __restrict__ W2p, const float* __restrict__ W2b,
    const float* __restrict__ W3w, const float* __restrict__ W3b,
    const float* __restrict__ ln1g, const float* __restrict__ ln1b,
    float* __restrict__ hVn1)
{
  __shared__ __align__(16) unsigned short Xs[48 * 136];   // hE bf16 (GEMM1 A)
  __shared__ __align__(16) unsigned short Ms[48 * 136];   // P3 gather, later G1-out, later matvec scratch
  __shared__ float maskv[48];
  __shared__ float dhs[128];      // s = masked colsum of gelu(G2)
  __shared__ float red[1];        // sum(mask)

  const int tid = threadIdx.x;
  const int lane = tid & 63;
  const int w = tid >> 6;
  const int rr = lane & 15;
  const int g4 = (lane >> 4) << 2;
  const int bidx = (blockIdx.x & 7) * 512 + (blockIdx.x >> 3);   // XCD swizzle
  const int bbase = bidx & ~2047;

  const float* hErow = hE + (size_t)bidx * 6144;
  const int* idxr = Eidx + (size_t)bidx * 48;

  // ---- staging: issue ALL loads, pin them live, then stores ----
  int jj[3];
  #pragma unroll
  for (int i = 0; i < 3; ++i) jj[i] = idxr[(tid + i * 256) >> 4];
  f32x4 tv[6];
  #pragma unroll
  for (int i = 0; i < 6; ++i) {
    const int e = tid + i * 256;
    tv[i] = *(const f32x4*)(hErow + (e >> 5) * 128 + ((e & 31) << 2));
  }
  short8 gv[3];
  #pragma unroll
  for (int i = 0; i < 3; ++i) {
    const int e = tid + i * 256;
    gv[i] = *(const short8*)(P3g + (size_t)(bbase + jj[i]) * 128 + ((e & 15) << 3));
  }
  // force all 9 loads' results simultaneously live -> batch issue
  asm volatile("" : "+v"(tv[0]), "+v"(tv[1]), "+v"(tv[2]),
                    "+v"(tv[3]), "+v"(tv[4]), "+v"(tv[5]),
                    "+v"(gv[0]), "+v"(gv[1]), "+v"(gv[2]));
  if (tid < 48) maskv[tid] = maskA[(size_t)bidx * 48 + tid];
  const float p1c0 = P1g[(size_t)bidx * 128 + w * 32 + rr];
  const float p1c1 = P1g[(size_t)bidx * 128 + w * 32 + 16 + rr];

  u32x2 pkv[6];
  #pragma unroll
  for (int i = 0; i < 6; ++i) {
    const int e = tid + i * 256, r = e >> 5, q = (e & 31) << 2;
    pkv[i][0] = pk2(tv[i][0], tv[i][1]);
    pkv[i][1] = pk2(tv[i][2], tv[i][3]);
    *(u32x2*)(&Xs[r * 136 + q]) = pkv[i];
  }
  #pragma unroll
  for (int i = 0; i < 3; ++i) {
    const int e = tid + i * 256;
    *(short8*)(&Ms[(e >> 4) * 136 + ((e & 15) << 3)]) = gv[i];
  }
  __syncthreads();                                        // B1

  if (tid == 0) {                                         // sum(mask), tiny
    float nm = 0.f;
    for (int i = 0; i < 48; ++i) nm += maskv[i];
    red[0] = nm;
  }

  // acc-init: P1 + gathered P3 (wave-own columns of Ms)
  f32x4 acc[3][2];
  #pragma unroll
  for (int m = 0; m < 3; ++m)
    #pragma unroll
    for (int c = 0; c < 2; ++c)
      #pragma unroll
      for (int r = 0; r < 4; ++r) {
        const int row = m * 16 + g4 + r;
        const int col = w * 32 + c * 16 + rr;
        acc[m][c][r] = (c ? p1c1 : p1c0) + bf2f(Ms[row * 136 + col]);
      }

  gemm_tiles<4, 3, 8>(Xs, 136, Wmidp, lane, w, acc);
  // gelu -> wave-own columns of Ms (same addrs this wave just read: race-free)
  #pragma unroll
  for (int m = 0; m < 3; ++m)
    #pragma unroll
    for (int c = 0; c < 2; ++c)
      #pragma unroll
      for (int r = 0; r < 4; ++r) {
        const int row = m * 16 + g4 + r;
        Ms[row * 136 + w * 32 + c * 16 + rr] = f2bf(gelu_f(acc[m][c][r]));
      }
  __syncthreads();                                        // B2

  // hEb side-write (deferred): drains under GEMM2's MFMA
  if constexpr (HEB) {
    #pragma unroll
    for (int i = 0; i < 6; ++i) {
      const int e = tid + i * 256, r = e >> 5, q = (e & 31) << 2;
      *(u32x2*)(hEbOut + (size_t)bidx * 6144 + r * 128 + q) = pkv[i];
    }
  }

  // GEMM2 (bias in C-init); gelu + masked colsum fully in-register
  {
    const float b0 = W2b[w * 32 + rr], b1 = W2b[w * 32 + 16 + rr];
    #pragma unroll
    for (int m = 0; m < 3; ++m) {
      acc[m][0] = (f32x4){b0, b0, b0, b0};
      acc[m][1] = (f32x4){b1, b1, b1, b1};
    }
  }
  gemm_tiles<4, 3, 8>(Ms, 136, W2p, lane, w, acc);
  {
    float p0 = 0.f, p1 = 0.f;
    #pragma unroll
    for (int m = 0; m < 3; ++m)
      #pragma unroll
      for (int r = 0; r < 4; ++r) {
        const float mk = maskv[m * 16 + g4 + r];
        p0 += mk * gelu_f(acc[m][0][r]);
        p1 += mk * gelu_f(acc[m][1][r]);
      }
    p0 += __shfl_xor(p0, 16); p0 += __shfl_xor(p0, 32);
    p1 += __shfl_xor(p1, 16); p1 += __shfl_xor(p1, 32);
    if (lane < 16) { dhs[w * 32 + lane] = p0; dhs[w * 32 + 16 + lane] = p1; }
  }
  __syncthreads();                                        // B3 (Ms reads done)

  // matvec dh = s @ W3 (split-k over 2 halves); partials into dead Ms as f32
  float* Msf = (float*)Ms;
  {
    const int col = tid & 127;
    const int k0 = (tid >> 7) * 64;
    float part = 0.f;
    #pragma unroll 8
    for (int k = 0; k < 64; ++k)
      part = fmaf(dhs[k0 + k], W3w[(size_t)(k0 + k) * 128 + col], part);
    Msf[tid] = part;
  }
  __syncthreads();                                        // B4

  if (w == 0) {                                           // wave 0 finishes LN1
    const float nm = red[0];
    const float dh0 = Msf[lane]      + Msf[128 + lane] + nm * W3b[lane];
    const float dh1 = Msf[64 + lane] + Msf[192 + lane] + nm * W3b[64 + lane];
    const float x0 = hV[(size_t)bidx * 128 + lane]      + dh0 * (1.0f / 30.0f);
    const float x1 = hV[(size_t)bidx * 128 + 64 + lane] + dh1 * (1.0f / 30.0f);
    float s = x0 + x1, sq = x0 * x0 + x1 * x1;
    #pragma unroll
    for (int msk = 1; msk < 64; msk <<= 1) {
      s += __shfl_xor(s, msk);
      sq += __shfl_xor(sq, msk);
    }
    const float mean = s * (1.f / 128.f);
    const float rstd = rsqrtf(sq * (1.f / 128.f) - mean * mean + 1e-5f);
    hVn1[(size_t)bidx * 128 + lane]      = (x0 - mean) * rstd * ln1g[lane] + ln1b[lane];
    hVn1[(size_t)bidx * 128 + 64 + lane] = (x1 - mean) * rstd * ln1g[64 + lane] + ln1b[64 + lane];
  }
}

// ---------------- FFN + LN2 + mask_V -> outV; fused P1/P3 for edge pass ------
__global__ __launch_bounds__(256) void k_ffn(
    const float* __restrict__ hVn1,
    const unsigned short* __restrict__ Winp, const float* __restrict__ Winb,
    const unsigned short* __restrict__ Woutp, const float* __restrict__ Woutb,
    const float* __restrict__ ln2g, const float* __restrict__ ln2b,
    const float* __restrict__ maskV,
    const unsigned short* __restrict__ W11tp, const unsigned short* __restrict__ W11bp,
    const float* __restrict__ W11b,
    float* __restrict__ outV, float* __restrict__ P1, unsigned short* __restrict__ P3)
{
  __shared__ __align__(16) unsigned short Xs2[16 * 136];
  __shared__ __align__(16) unsigned short Ys[16 * 520];
  __shared__ __align__(16) unsigned short Ts[16 * 136];
  __shared__ float Rs[16 * 128];

  const int tid = threadIdx.x;
  const int lane = tid & 63;
  const int w = tid >> 6;
  const int rr = lane & 15;
  const int kg = (lane >> 4) << 3;
  const int row0 = blockIdx.x * 16;

  for (int e = tid; e < 512; e += 256) {
    const int r = e >> 5, q = (e & 31) << 2;
    float4 v = *(const float4*)(hVn1 + (size_t)(row0 + r) * 128 + q);
    u32x2 pk; pk[0] = pk2(v.x, v.y); pk[1] = pk2(v.z, v.w);
    *(u32x2*)(&Xs2[r * 136 + q]) = pk;
  }
  __syncthreads();

  const f32x4 zf = {0.f, 0.f, 0.f, 0.f};
  f32x4 acc1[8];
  #pragma unroll
  for (int c = 0; c < 8; ++c) acc1[c] = zf;
  #pragma unroll
  for (int t = 0; t < 4; ++t) {
    const short8 a = *(const short8*)(&Xs2[rr * 136 + t * 32 + kg]);
    #pragma unroll
    for (int c = 0; c < 8; ++c) {
      const short8 bf = *(const short8*)(Winp + ((size_t)(t * 32 + w * 8 + c) * 64 + lane) * 8);
      acc1[c] = mfma16(a, bf, acc1[c]);
    }
  }
  #pragma unroll
  for (int c = 0; c < 8; ++c) {
    const int col = w * 128 + c * 16 + rr;
    const float bias = Winb[col];
    #pragma unroll
    for (int r = 0; r < 4; ++r) {
      const int row = ((lane >> 4) << 2) + r;
      Ys[row * 520 + col] = f2bf(gelu_f(acc1[c][r] + bias));
    }
  }
  __syncthreads();

  f32x4 acc2[2];
  acc2[0] = zf; acc2[1] = zf;
  #pragma unroll 4
  for (int t = 0; t < 16; ++t) {
    const short8 a = *(const short8*)(&Ys[rr * 520 + t * 32 + kg]);
    #pragma unroll
    for (int c = 0; c < 2; ++c) {
      const short8 bf = *(const short8*)(Woutp + ((size_t)(t * 8 + w * 2 + c) * 64 + lane) * 8);
      acc2[c] = mfma16(a, bf, acc2[c]);
    }
  }
  #pragma unroll
  for (int c = 0; c < 2; ++c) {
    const int col = w * 32 + c * 16 + rr;
    const float bias = Woutb[col];
    #pragma unroll
    for (int r = 0; r < 4; ++r) {
      const int row = ((lane >> 4) << 2) + r;
      Rs[row * 128 + col] = acc2[c][r] + bias + hVn1[(size_t)(row0 + row) * 128 + col];
    }
  }
  __syncthreads();

  const float g0 = ln2g[lane], g1 = ln2g[lane + 64];
  const float be0 = ln2b[lane], be1 = ln2b[lane + 64];
  for (int i = 0; i < 4; ++i) {
    const int row = w * 4 + i;
    const int grow = row0 + row;
    const float x0 = Rs[row * 128 + lane], x1 = Rs[row * 128 + 64 + lane];
    float s = x0 + x1, q2 = x0 * x0 + x1 * x1;
    #pragma unroll
    for (int msk = 1; msk < 64; msk <<= 1) {
      s += __shfl_xor(s, msk);
      q2 += __shfl_xor(q2, msk);
    }
    const float mean = s * (1.f / 128.f);
    const float rstd = rsqrtf(q2 * (1.f / 128.f) - mean * mean + 1e-5f);
    const float mv = maskV[grow];
    const float y0 = ((x0 - mean) * rstd * g0 + be0) * mv;
    const float y1 = ((x1 - mean) * rstd * g1 + be1) * mv;
    outV[(size_t)grow * 128 + lane]      = y0;
    outV[(size_t)grow * 128 + 64 + lane] = y1;
    Ts[row * 136 + lane]      = f2bf(y0);
    Ts[row * 136 + 64 + lane] = f2bf(y1);
  }
  __syncthreads();

  // fused k_pre for the edge pass: P1 = outV@W11top + b, P3 = outV@W11bot
  f32x4 a0[2] = {zf, zf}, a1[2] = {zf, zf};
  #pragma unroll
  for (int t = 0; t < 4; ++t) {
    const short8 a = *(const short8*)(&Ts[rr * 136 + t * 32 + kg]);
    #pragma unroll
    for (int c = 0; c < 2; ++c) {
      short8 bt = *(const short8*)(W11tp + ((size_t)(t * 8 + (w * 2 + c)) * 64 + lane) * 8);
      a0[c] = mfma16(a, bt, a0[c]);
      short8 bb = *(const short8*)(W11bp + ((size_t)(t * 8 + (w * 2 + c)) * 64 + lane) * 8);
      a1[c] = mfma16(a, bb, a1[c]);
    }
  }
  #pragma unroll
  for (int c = 0; c < 2; ++c) {
    const int col = w * 32 + c * 16 + rr;
    const float b = W11b[col];
    #pragma unroll
    for (int r = 0; r < 4; ++r) {
      const int row = row0 + ((lane >> 4) << 2) + r;
      P1[(size_t)row * 128 + col] = a0[c][r] + b;
      P3[(size_t)row * 128 + col] = f2bf(a1[c][r]);
    }
  }
}

// ---------------- edge update + LN3 -> outE (load-all staging + pins) --------
template<bool HEB>
__global__ __launch_bounds__(256) void k_edge_t(
    const float* __restrict__ hE, const unsigned short* __restrict__ hEb,
    const int* __restrict__ Eidx,
    const float* __restrict__ P1g, const unsigned short* __restrict__ P3g,
    const unsigned short* __restrict__ Wmidp,
    const unsigned short* __restrict__ W12p, const float* __restrict__ W12b,
    const unsigned short* __restrict__ W13p, const float* __restrict__ W13b,
    const float* __restrict__ ln3g, const float* __restrict__ ln3b,
    float* __restrict__ outE)
{
  __shared__ __align__(16) unsigned short Xs[48 * 136];   // hE bf16, later GEMM2-out
  __shared__ __align__(16) unsigned short Ms[48 * 136];   // P3 gather, later GEMM1-out
  __shared__ float sums[48 * 4];
  __shared__ float sqs[48 * 4];
  __shared__ float mr[96];

  const int tid = threadIdx.x;
  const int lane = tid & 63;
  const int w = tid >> 6;
  const int rr = lane & 15;
  const int g4 = (lane >> 4) << 2;
  const int bidx = (blockIdx.x & 7) * 512 + (blockIdx.x >> 3);   // XCD swizzle
  const int bbase = bidx & ~2047;

  const int* idxr = Eidx + (size_t)bidx * 48;

  // ---- staging: issue ALL loads, pin them live, then stores ----
  int jj[3];
  #pragma unroll
  for (int i = 0; i < 3; ++i) jj[i] = idxr[(tid + i * 256) >> 4];

  short8 tvb[3]; f32x4 tvf[6];
  if constexpr (HEB) {
    #pragma unroll
    for (int i = 0; i < 3; ++i) {
      const int e = tid + i * 256;
      tvb[i] = *(const short8*)(hEb + (size_t)bidx * 6144 + (e >> 4) * 128 + ((e & 15) << 3));
    }
  } else {
    #pragma unroll
    for (int i = 0; i < 6; ++i) {
      const int e = tid + i * 256;
      tvf[i] = *(const f32x4*)(hE + (size_t)bidx * 6144 + (e >> 5) * 128 + ((e & 31) << 2));
    }
  }
  short8 gv[3];
  #pragma unroll
  for (int i = 0; i < 3; ++i) {
    const int e = tid + i * 256;
    gv[i] = *(const short8*)(P3g + (size_t)(bbase + jj[i]) * 128 + ((e & 15) << 3));
  }
  if constexpr (HEB) {
    asm volatile("" : "+v"(tvb[0]), "+v"(tvb[1]), "+v"(tvb[2]),
                      "+v"(gv[0]), "+v"(gv[1]), "+v"(gv[2]));
  } else {
    asm volatile("" : "+v"(tvf[0]), "+v"(tvf[1]), "+v"(tvf[2]),
                      "+v"(tvf[3]), "+v"(tvf[4]), "+v"(tvf[5]),
                      "+v"(gv[0]), "+v"(gv[1]), "+v"(gv[2]));
  }
  const float p1c0 = P1g[(size_t)bidx * 128 + w * 32 + rr];
  const float p1c1 = P1g[(size_t)bidx * 128 + w * 32 + 16 + rr];

  if constexpr (HEB) {
    #pragma unroll
    for (int i = 0; i < 3; ++i) {
      const int e = tid + i * 256;
      *(short8*)(&Xs[(e >> 4) * 136 + ((e & 15) << 3)]) = tvb[i];
    }
  } else {
    #pragma unroll
    for (int i = 0; i < 6; ++i) {
      const int e = tid + i * 256, r = e >> 5, q = (e & 31) << 2;
      u32x2 pk; pk[0] = pk2(tvf[i][0], tvf[i][1]); pk[1] = pk2(tvf[i][2], tvf[i][3]);
      *(u32x2*)(&Xs[r * 136 + q]) = pk;
    }
  }
  #pragma unroll
  for (int i = 0; i < 3; ++i) {
    const int e = tid + i * 256;
    *(short8*)(&Ms[(e >> 4) * 136 + ((e & 15) << 3)]) = gv[i];
  }
  __syncthreads();                                        // B1

  // residual capture (wave-own cols) + acc-init
  f32x4 acc[3][2];
  float res[3][2][4];
  #pragma unroll
  for (int m = 0; m < 3; ++m)
    #pragma unroll
    for (int c = 0; c < 2; ++c)
      #pragma unroll
      for (int r = 0; r < 4; ++r) {
        const int row = m * 16 + g4 + r;
        const int col = w * 32 + c * 16 + rr;
        acc[m][c][r] = (c ? p1c1 : p1c0) + bf2f(Ms[row * 136 + col]);
        res[m][c][r] = bf2f(Xs[row * 136 + col]);
      }

  gemm_tiles<4, 3, 8>(Xs, 136, Wmidp, lane, w, acc);
  #pragma unroll
  for (int m = 0; m < 3; ++m)
    #pragma unroll
    for (int c = 0; c < 2; ++c)
      #pragma unroll
      for (int r = 0; r < 4; ++r) {
        const int row = m * 16 + g4 + r;
        Ms[row * 136 + w * 32 + c * 16 + rr] = f2bf(gelu_f(acc[m][c][r]));
      }
  __syncthreads();                                        // B2

  const f32x4 zf = {0.f, 0.f, 0.f, 0.f};
  #pragma unroll
  for (int m = 0; m < 3; ++m) { acc[m][0] = zf; acc[m][1] = zf; }
  gemm_tiles<4, 3, 8>(Ms, 136, W12p, lane, w, acc);
  {
    const float b0 = W12b[w * 32 + rr], b1 = W12b[w * 32 + 16 + rr];
    #pragma unroll
    for (int m = 0; m < 3; ++m)
      #pragma unroll
      for (int c = 0; c < 2; ++c)
        #pragma unroll
        for (int r = 0; r < 4; ++r) {
          const int row = m * 16 + g4 + r;
          Xs[row * 136 + w * 32 + c * 16 + rr] = f2bf(gelu_f(acc[m][c][r] + (c ? b1 : b0)));
        }
  }
  __syncthreads();                                        // B3

  #pragma unroll
  for (int m = 0; m < 3; ++m) { acc[m][0] = zf; acc[m][1] = zf; }
  gemm_tiles<4, 3, 8>(Xs, 136, W13p, lane, w, acc);

  {
    const float b0 = W13b[w * 32 + rr], b1 = W13b[w * 32 + 16 + rr];
    #pragma unroll
    for (int m = 0; m < 3; ++m)
      #pragma unroll
      for (int r = 0; r < 4; ++r) {
        const int row = m * 16 + g4 + r;
        acc[m][0][r] += b0 + res[m][0][r];
        acc[m][1][r] += b1 + res[m][1][r];
        float s = acc[m][0][r] + acc[m][1][r];
        float q2 = acc[m][0][r] * acc[m][0][r] + acc[m][1][r] * acc[m][1][r];
        s += __shfl_xor(s, 1); q2 += __shfl_xor(q2, 1);
        s += __shfl_xor(s, 2); q2 += __shfl_xor(q2, 2);
        s += __shfl_xor(s, 4); q2 += __shfl_xor(q2, 4);
        s += __shfl_xor(s, 8); q2 += __shfl_xor(q2, 8);
        if ((lane & 15) == 0) { sums[row * 4 + w] = s; sqs[row * 4 + w] = q2; }
      }
  }
  __syncthreads();                                        // B4
  if (tid < 48) {
    const float s = sums[tid * 4] + sums[tid * 4 + 1] + sums[tid * 4 + 2] + sums[tid * 4 + 3];
    const float q2 = sqs[tid * 4] + sqs[tid * 4 + 1] + sqs[tid * 4 + 2] + sqs[tid * 4 + 3];
    const float mean = s * (1.f / 128.f);
    mr[tid * 2] = mean;
    mr[tid * 2 + 1] = rsqrtf(q2 * (1.f / 128.f) - mean * mean + 1e-5f);
  }
  __syncthreads();                                        // B5
  {
    const float g0 = ln3g[w * 32 + rr], g1 = ln3g[w * 32 + 16 + rr];
    const float be0 = ln3b[w * 32 + rr], be1 = ln3b[w * 32 + 16 + rr];
    #pragma unroll
    for (int m = 0; m < 3; ++m)
      #pragma unroll
      for (int r = 0; r < 4; ++r) {
        const int row = m * 16 + g4 + r;
        const float mean = mr[row * 2], rstd = mr[row * 2 + 1];
        const size_t base = (size_t)bidx * 6144 + (size_t)row * 128 + w * 32 + rr;
        outE[base]      = (acc[m][0][r] - mean) * rstd * g0 + be0;
        outE[base + 16] = (acc[m][1][r] - mean) * rstd * g1 + be1;
      }
  }
}

extern "C" void kernel_launch(void* const* d_in, const int* in_sizes, int n_in,
                              void* d_out, int out_size, void* d_ws, size_t ws_size,
                              hipStream_t stream) {
  const float* hV    = (const float*)d_in[0];
  const float* hE    = (const float*)d_in[1];
  const int*   Eidx  = (const int*)d_in[2];
  const float* maskV = (const float*)d_in[3];
  const float* maskA = (const float*)d_in[4];
  const float* W1w  = (const float*)d_in[5];  const float* W1b  = (const float*)d_in[6];
  const float* W2w  = (const float*)d_in[7];  const float* W2b  = (const float*)d_in[8];
  const float* W3w  = (const float*)d_in[9];  const float* W3b  = (const float*)d_in[10];
  const float* W11w = (const float*)d_in[11]; const float* W11b = (const float*)d_in[12];
  const float* W12w = (const float*)d_in[13]; const float* W12b = (const float*)d_in[14];
  const float* W13w = (const float*)d_in[15]; const float* W13b = (const float*)d_in[16];
  const float* Winw = (const float*)d_in[17]; const float* Winb = (const float*)d_in[18];
  const float* Woutw= (const float*)d_in[19]; const float* Woutb= (const float*)d_in[20];
  const float* ln1g = (const float*)d_in[21]; const float* ln1b = (const float*)d_in[22];
  const float* ln2g = (const float*)d_in[23]; const float* ln2b = (const float*)d_in[24];
  const float* ln3g = (const float*)d_in[25]; const float* ln3b = (const float*)d_in[26];

  float* outV = (float*)d_out;                       // [4096,128]
  float* outE = outV + (size_t)4096 * 128;           // [4096*48,128]

  char* ws = (char*)d_ws;
  float* hVn1 = (float*)ws;                                  // 2 MB
  float* P1   = (float*)(ws + (size_t)2 * 1024 * 1024);      // 2 MB
  unsigned short* P3 = (unsigned short*)(ws + (size_t)4 * 1024 * 1024);  // 1 MB
  unsigned short* Wp = (unsigned short*)(ws + (size_t)5 * 1024 * 1024);  // 576 KB
  unsigned short* hEb = (unsigned short*)(ws + (size_t)6 * 1024 * 1024); // 48 MB bf16

  const size_t NEED = (size_t)6 * 1024 * 1024 + (size_t)4096 * 48 * 128 * 2;
  const bool heb = ws_size >= NEED;

  const unsigned short* W1top_p  = Wp;
  const unsigned short* W1mid_p  = Wp + (size_t)2048 * 8;
  const unsigned short* W1bot_p  = Wp + (size_t)4096 * 8;
  const unsigned short* W2p      = Wp + (size_t)6144 * 8;
  const unsigned short* W11top_p = Wp + (size_t)10240 * 8;
  const unsigned short* W11mid_p = Wp + (size_t)12288 * 8;
  const unsigned short* W11bot_p = Wp + (size_t)14336 * 8;
  const unsigned short* W12p     = Wp + (size_t)16384 * 8;
  const unsigned short* W13p     = Wp + (size_t)18432 * 8;
  const unsigned short* Winp     = Wp + (size_t)20480 * 8;
  const unsigned short* Woutp    = Wp + (size_t)28672 * 8;

  k_pack<<<144, 256, 0, stream>>>(W1w, W2w, W3w, W11w, W12w, W13w, Winw, Woutw, Wp);
  k_pre<<<256, 256, 0, stream>>>(hV, W1top_p, W1bot_p, W1b, P1, P3);

  if (heb)
    k_node_t<true><<<4096, 256, 0, stream>>>(hV, hE, hEb, Eidx, maskA, P1, P3,
                                             W1mid_p, W2p, W2b, W3w, W3b,
                                             ln1g, ln1b, hVn1);
  else
    k_node_t<false><<<4096, 256, 0, stream>>>(hV, hE, hEb, Eidx, maskA, P1, P3,
                                              W1mid_p, W2p, W2b, W3w, W3b,
                                              ln1g, ln1b, hVn1);

  k_ffn<<<256, 256, 0, stream>>>(hVn1, Winp, Winb, Woutp, Woutb,
                                 ln2g, ln2b, maskV,
                                 W11top_p, W11bot_p, W11b,
                                 outV, P1, P3);

  if (heb)
    k_edge_t<true><<<4096, 256, 0, stream>>>(hE, hEb, Eidx, P1, P3,
                                             W11mid_p, W12p, W12b, W13p, W13b,
                                             ln3g, ln3b, outE);
  else
    k_edge_t<false><<<4096, 256, 0, stream>>>(hE, hEb, Eidx, P1, P3,
                                              W11mid_p, W12p, W12b, W13p, W13b,
                                              ln3g, ln3b, outE);
}

// Round 18
// 127.042 us; speedup vs baseline: 1.0298x; 1.0298x over previous
//
#include <hip/hip_runtime.h>
#include <hip/hip_bf16.h>

#define DEVINL __device__ __forceinline__

typedef __attribute__((ext_vector_type(8))) short short8;
typedef __attribute__((ext_vector_type(4))) float f32x4;

DEVINL unsigned short f2bf(float x) {
  __hip_bfloat16 h = __float2bfloat16(x);
  return __builtin_bit_cast(unsigned short, h);
}
DEVINL unsigned int pk2(float lo, float hi) {
  return (unsigned int)f2bf(lo) | ((unsigned int)f2bf(hi) << 16);
}
DEVINL float bf2f(unsigned short h) {
  union { unsigned int u; float f; } c; c.u = ((unsigned int)h) << 16;
  return c.f;
}
// tanh-form GELU (branchless): |diff vs erf-GELU| <~3e-3, far under threshold.
DEVINL float gelu_f(float x) {
  const float u = x * x;
  const float y = x * (0.7978845608f + 0.0356774081f * u);
  const float e = __expf(-2.0f * y);
  return x * __builtin_amdgcn_rcpf(1.0f + e);
}
DEVINL f32x4 mfma16(short8 a, short8 b, f32x4 c) {
  return __builtin_amdgcn_mfma_f32_16x16x32_bf16(a, b, c, 0, 0, 0);
}

// GEMM from LDS A-tile (row-major, ldx bf16 elems) with pre-packed B frags.
template<int KSTEPS, int MT, int NT>
DEVINL void gemm_tiles(const unsigned short* Xl, int ldx,
                       const unsigned short* __restrict__ Wp,
                       int lane, int w, f32x4 (&acc)[MT][2])
{
  const int rr = lane & 15;
  const int kg = (lane >> 4) << 3;
  __builtin_amdgcn_s_setprio(1);
  #pragma unroll
  for (int t = 0; t < KSTEPS; ++t) {
    short8 a[MT];
    #pragma unroll
    for (int m = 0; m < MT; ++m)
      a[m] = *(const short8*)(Xl + (m * 16 + rr) * ldx + t * 32 + kg);
    #pragma unroll
    for (int c = 0; c < 2; ++c) {
      short8 bf = *(const short8*)(Wp + ((size_t)(t * NT + (w * 2 + c)) * 64 + lane) * 8);
      #pragma unroll
      for (int m = 0; m < MT; ++m)
        acc[m][c] = mfma16(a[m], bf, acc[m][c]);
    }
  }
  __builtin_amdgcn_s_setprio(0);
}

// ---- pack all weights -> bf16 MFMA B-fragments in ws ------------------------
__global__ __launch_bounds__(256) void k_pack(
    const float* __restrict__ W1w,  const float* __restrict__ W2w,
    const float* __restrict__ W3w,  const float* __restrict__ W11w,
    const float* __restrict__ W12w, const float* __restrict__ W13w,
    const float* __restrict__ Winw, const float* __restrict__ Woutw,
    unsigned short* __restrict__ dst)
{
  const int f = blockIdx.x * 256 + threadIdx.x;
  if (f >= 36864) return;
  const float* src; int row0 = 0, Ncols = 128, NT = 8, lf;
  if (f < 20480) {
    const int seg = f >> 11; lf = f & 2047;
    switch (seg) {
      case 0: src = W1w;  row0 = 0;   break;
      case 1: src = W1w;  row0 = 128; break;
      case 2: src = W1w;  row0 = 256; break;
      case 3: src = W2w;  break;
      case 4: src = W3w;  break;
      case 5: src = W11w; row0 = 0;   break;
      case 6: src = W11w; row0 = 128; break;
      case 7: src = W11w; row0 = 256; break;
      case 8: src = W12w; break;
      default: src = W13w; break;
    }
  } else if (f < 28672) { src = Winw; lf = f - 20480; NT = 32; Ncols = 512; }
  else { src = Woutw; lf = f - 28672; }
  const int l = lf & 63;
  const int g = lf >> 6;
  const int c = g % NT;
  const int t = g / NT;
  const int r0 = row0 + t * 32 + ((l >> 4) << 3);
  const int col = c * 16 + (l & 15);
  short8 vv;
  #pragma unroll
  for (int b = 0; b < 8; ++b)
    vv[b] = (short)f2bf(src[(size_t)(r0 + b) * Ncols + col]);
  *(short8*)(dst + (size_t)f * 8) = vv;
}

// ---- precompute P1 = X@Wtop + bias (f32), P3 = X@Wbot (bf16), X:[4096,128] --
__global__ __launch_bounds__(256) void k_pre(
    const float* __restrict__ X,
    const unsigned short* __restrict__ Wtp,
    const unsigned short* __restrict__ Wbp,
    const float* __restrict__ bias,
    float* __restrict__ P1, unsigned short* __restrict__ P3)
{
  __shared__ __align__(16) unsigned short Xs2[16 * 136];
  const int tid = threadIdx.x;
  const int lane = tid & 63;
  const int w = tid >> 6;
  const int rr = lane & 15;
  const int kg = (lane >> 4) << 3;
  const int row0 = blockIdx.x * 16;

  for (int e = tid; e < 512; e += 256) {
    const int r = e >> 5, q = (e & 31) << 2;
    float4 v = *(const float4*)(X + (size_t)(row0 + r) * 128 + q);
    uint2 pk; pk.x = pk2(v.x, v.y); pk.y = pk2(v.z, v.w);
    *(uint2*)(&Xs2[r * 136 + q]) = pk;
  }
  __syncthreads();

  const f32x4 zf = {0.f, 0.f, 0.f, 0.f};
  f32x4 a0[2] = {zf, zf}, a1[2] = {zf, zf};
  #pragma unroll
  for (int t = 0; t < 4; ++t) {
    const short8 a = *(const short8*)(&Xs2[rr * 136 + t * 32 + kg]);
    #pragma unroll
    for (int c = 0; c < 2; ++c) {
      short8 bt = *(const short8*)(Wtp + ((size_t)(t * 8 + (w * 2 + c)) * 64 + lane) * 8);
      a0[c] = mfma16(a, bt, a0[c]);
      short8 bb = *(const short8*)(Wbp + ((size_t)(t * 8 + (w * 2 + c)) * 64 + lane) * 8);
      a1[c] = mfma16(a, bb, a1[c]);
    }
  }
  #pragma unroll
  for (int c = 0; c < 2; ++c) {
    const int col = w * 32 + c * 16 + rr;
    const float b = bias[col];
    #pragma unroll
    for (int r = 0; r < 4; ++r) {
      const int row = row0 + ((lane >> 4) << 2) + r;
      P1[(size_t)row * 128 + col] = a0[c][r] + b;
      P3[(size_t)row * 128 + col] = f2bf(a1[c][r]);
    }
  }
}

// ---------------- node message pass + LN1 -> hVn1; side-writes hEb -----------
// GEMM3 collapsed: dh = (sum_k mask[k]*gelu(G2)[k,:]) @ W3 + (sum mask)*b3
// Staging: load-all-then-store-all, enforced by sched_barrier(0).
template<bool HEB>
__global__ __launch_bounds__(256, 4) void k_node_t(
    const float* __restrict__ hV, const float* __restrict__ hE,
    unsigned short* __restrict__ hEbOut,
    const int* __restrict__ Eidx, const float* __restrict__ maskA,
    const float* __restrict__ P1g, const unsigned short* __restrict__ P3g,
    const unsigned short* __restrict__ Wmidp,
    const unsigned short* __restrict__ W2p, const float* __restrict__ W2b,
    const float* __restrict__ W3w, const float* __restrict__ W3b,
    const float* __restrict__ ln1g, const float* __restrict__ ln1b,
    float* __restrict__ hVn1)
{
  __shared__ __align__(16) unsigned short Xs[48 * 136];   // hE bf16 (GEMM1 A)
  __shared__ __align__(16) unsigned short Ms[48 * 136];   // P3 gather, later G1-out, later matvec scratch
  __shared__ float maskv[48];
  __shared__ float dhs[128];      // s = masked colsum of gelu(G2)
  __shared__ float red[1];        // sum(mask)

  const int tid = threadIdx.x;
  const int lane = tid & 63;
  const int w = tid >> 6;
  const int rr = lane & 15;
  const int g4 = (lane >> 4) << 2;
  const int bidx = (blockIdx.x & 7) * 512 + (blockIdx.x >> 3);   // XCD swizzle
  const int bbase = bidx & ~2047;

  const float* hErow = hE + (size_t)bidx * 6144;
  const int* idxr = Eidx + (size_t)bidx * 48;

  // ---- staging: issue ALL loads, fence, then stores ----
  int jj[3];
  #pragma unroll
  for (int i = 0; i < 3; ++i) jj[i] = idxr[(tid + i * 256) >> 4];
  float4 tv[6];
  #pragma unroll
  for (int i = 0; i < 6; ++i) {
    const int e = tid + i * 256;
    tv[i] = *(const float4*)(hErow + (e >> 5) * 128 + ((e & 31) << 2));
  }
  short8 gv[3];
  #pragma unroll
  for (int i = 0; i < 3; ++i) {
    const int e = tid + i * 256;
    gv[i] = *(const short8*)(P3g + (size_t)(bbase + jj[i]) * 128 + ((e & 15) << 3));
  }
  __builtin_amdgcn_sched_barrier(0);   // loads above, consumers below
  if (tid < 48) maskv[tid] = maskA[(size_t)bidx * 48 + tid];
  const float p1c0 = P1g[(size_t)bidx * 128 + w * 32 + rr];
  const float p1c1 = P1g[(size_t)bidx * 128 + w * 32 + 16 + rr];

  #pragma unroll
  for (int i = 0; i < 6; ++i) {
    const int e = tid + i * 256, r = e >> 5, q = (e & 31) << 2;
    uint2 pk; pk.x = pk2(tv[i].x, tv[i].y); pk.y = pk2(tv[i].z, tv[i].w);
    *(uint2*)(&Xs[r * 136 + q]) = pk;
    if constexpr (HEB)
      *(uint2*)(hEbOut + (size_t)bidx * 6144 + r * 128 + q) = pk;
  }
  #pragma unroll
  for (int i = 0; i < 3; ++i) {
    const int e = tid + i * 256;
    *(short8*)(&Ms[(e >> 4) * 136 + ((e & 15) << 3)]) = gv[i];
  }
  __syncthreads();                                        // B1

  if (tid == 0) {                                         // sum(mask), tiny
    float nm = 0.f;
    for (int i = 0; i < 48; ++i) nm += maskv[i];
    red[0] = nm;
  }

  // acc-init: P1 + gathered P3 (wave-own columns of Ms)
  f32x4 acc[3][2];
  #pragma unroll
  for (int m = 0; m < 3; ++m)
    #pragma unroll
    for (int c = 0; c < 2; ++c)
      #pragma unroll
      for (int r = 0; r < 4; ++r) {
        const int row = m * 16 + g4 + r;
        const int col = w * 32 + c * 16 + rr;
        acc[m][c][r] = (c ? p1c1 : p1c0) + bf2f(Ms[row * 136 + col]);
      }

  gemm_tiles<4, 3, 8>(Xs, 136, Wmidp, lane, w, acc);
  // gelu -> wave-own columns of Ms (same addrs this wave just read: race-free)
  #pragma unroll
  for (int m = 0; m < 3; ++m)
    #pragma unroll
    for (int c = 0; c < 2; ++c)
      #pragma unroll
      for (int r = 0; r < 4; ++r) {
        const int row = m * 16 + g4 + r;
        Ms[row * 136 + w * 32 + c * 16 + rr] = f2bf(gelu_f(acc[m][c][r]));
      }
  __syncthreads();                                        // B2

  // GEMM2 (bias in C-init); gelu + masked colsum fully in-register
  {
    const float b0 = W2b[w * 32 + rr], b1 = W2b[w * 32 + 16 + rr];
    #pragma unroll
    for (int m = 0; m < 3; ++m) {
      acc[m][0] = (f32x4){b0, b0, b0, b0};
      acc[m][1] = (f32x4){b1, b1, b1, b1};
    }
  }
  gemm_tiles<4, 3, 8>(Ms, 136, W2p, lane, w, acc);
  {
    float p0 = 0.f, p1 = 0.f;
    #pragma unroll
    for (int m = 0; m < 3; ++m)
      #pragma unroll
      for (int r = 0; r < 4; ++r) {
        const float mk = maskv[m * 16 + g4 + r];
        p0 += mk * gelu_f(acc[m][0][r]);
        p1 += mk * gelu_f(acc[m][1][r]);
      }
    p0 += __shfl_xor(p0, 16); p0 += __shfl_xor(p0, 32);
    p1 += __shfl_xor(p1, 16); p1 += __shfl_xor(p1, 32);
    if (lane < 16) { dhs[w * 32 + lane] = p0; dhs[w * 32 + 16 + lane] = p1; }
  }
  __syncthreads();                                        // B3 (Ms reads done)

  // matvec dh = s @ W3 (split-k over 2 halves); partials into dead Ms as f32
  float* Msf = (float*)Ms;
  {
    const int col = tid & 127;
    const int k0 = (tid >> 7) * 64;
    float part = 0.f;
    #pragma unroll 8
    for (int k = 0; k < 64; ++k)
      part = fmaf(dhs[k0 + k], W3w[(size_t)(k0 + k) * 128 + col], part);
    Msf[tid] = part;
  }
  __syncthreads();                                        // B4

  if (w == 0) {                                           // wave 0 finishes LN1
    const float nm = red[0];
    const float dh0 = Msf[lane]      + Msf[128 + lane] + nm * W3b[lane];
    const float dh1 = Msf[64 + lane] + Msf[192 + lane] + nm * W3b[64 + lane];
    const float x0 = hV[(size_t)bidx * 128 + lane]      + dh0 * (1.0f / 30.0f);
    const float x1 = hV[(size_t)bidx * 128 + 64 + lane] + dh1 * (1.0f / 30.0f);
    float s = x0 + x1, sq = x0 * x0 + x1 * x1;
    #pragma unroll
    for (int msk = 1; msk < 64; msk <<= 1) {
      s += __shfl_xor(s, msk);
      sq += __shfl_xor(sq, msk);
    }
    const float mean = s * (1.f / 128.f);
    const float rstd = rsqrtf(sq * (1.f / 128.f) - mean * mean + 1e-5f);
    hVn1[(size_t)bidx * 128 + lane]      = (x0 - mean) * rstd * ln1g[lane] + ln1b[lane];
    hVn1[(size_t)bidx * 128 + 64 + lane] = (x1 - mean) * rstd * ln1g[64 + lane] + ln1b[64 + lane];
  }
}

// ---------------- FFN + LN2 + mask_V -> outV; fused P1/P3 for edge pass ------
__global__ __launch_bounds__(256) void k_ffn(
    const float* __restrict__ hVn1,
    const unsigned short* __restrict__ Winp, const float* __restrict__ Winb,
    const unsigned short* __restrict__ Woutp, const float* __restrict__ Woutb,
    const float* __restrict__ ln2g, const float* __restrict__ ln2b,
    const float* __restrict__ maskV,
    const unsigned short* __restrict__ W11tp, const unsigned short* __restrict__ W11bp,
    const float* __restrict__ W11b,
    float* __restrict__ outV, float* __restrict__ P1, unsigned short* __restrict__ P3)
{
  __shared__ __align__(16) unsigned short Xs2[16 * 136];
  __shared__ __align__(16) unsigned short Ys[16 * 520];
  __shared__ __align__(16) unsigned short Ts[16 * 136];
  __shared__ float Rs[16 * 128];

  const int tid = threadIdx.x;
  const int lane = tid & 63;
  const int w = tid >> 6;
  const int rr = lane & 15;
  const int kg = (lane >> 4) << 3;
  const int row0 = blockIdx.x * 16;

  for (int e = tid; e < 512; e += 256) {
    const int r = e >> 5, q = (e & 31) << 2;
    float4 v = *(const float4*)(hVn1 + (size_t)(row0 + r) * 128 + q);
    uint2 pk; pk.x = pk2(v.x, v.y); pk.y = pk2(v.z, v.w);
    *(uint2*)(&Xs2[r * 136 + q]) = pk;
  }
  __syncthreads();

  const f32x4 zf = {0.f, 0.f, 0.f, 0.f};
  f32x4 acc1[8];
  #pragma unroll
  for (int c = 0; c < 8; ++c) acc1[c] = zf;
  #pragma unroll
  for (int t = 0; t < 4; ++t) {
    const short8 a = *(const short8*)(&Xs2[rr * 136 + t * 32 + kg]);
    #pragma unroll
    for (int c = 0; c < 8; ++c) {
      const short8 bf = *(const short8*)(Winp + ((size_t)(t * 32 + w * 8 + c) * 64 + lane) * 8);
      acc1[c] = mfma16(a, bf, acc1[c]);
    }
  }
  #pragma unroll
  for (int c = 0; c < 8; ++c) {
    const int col = w * 128 + c * 16 + rr;
    const float bias = Winb[col];
    #pragma unroll
    for (int r = 0; r < 4; ++r) {
      const int row = ((lane >> 4) << 2) + r;
      Ys[row * 520 + col] = f2bf(gelu_f(acc1[c][r] + bias));
    }
  }
  __syncthreads();

  f32x4 acc2[2];
  acc2[0] = zf; acc2[1] = zf;
  #pragma unroll 4
  for (int t = 0; t < 16; ++t) {
    const short8 a = *(const short8*)(&Ys[rr * 520 + t * 32 + kg]);
    #pragma unroll
    for (int c = 0; c < 2; ++c) {
      const short8 bf = *(const short8*)(Woutp + ((size_t)(t * 8 + w * 2 + c) * 64 + lane) * 8);
      acc2[c] = mfma16(a, bf, acc2[c]);
    }
  }
  #pragma unroll
  for (int c = 0; c < 2; ++c) {
    const int col = w * 32 + c * 16 + rr;
    const float bias = Woutb[col];
    #pragma unroll
    for (int r = 0; r < 4; ++r) {
      const int row = ((lane >> 4) << 2) + r;
      Rs[row * 128 + col] = acc2[c][r] + bias + hVn1[(size_t)(row0 + row) * 128 + col];
    }
  }
  __syncthreads();

  const float g0 = ln2g[lane], g1 = ln2g[lane + 64];
  const float be0 = ln2b[lane], be1 = ln2b[lane + 64];
  for (int i = 0; i < 4; ++i) {
    const int row = w * 4 + i;
    const int grow = row0 + row;
    const float x0 = Rs[row * 128 + lane], x1 = Rs[row * 128 + 64 + lane];
    float s = x0 + x1, q2 = x0 * x0 + x1 * x1;
    #pragma unroll
    for (int msk = 1; msk < 64; msk <<= 1) {
      s += __shfl_xor(s, msk);
      q2 += __shfl_xor(q2, msk);
    }
    const float mean = s * (1.f / 128.f);
    const float rstd = rsqrtf(q2 * (1.f / 128.f) - mean * mean + 1e-5f);
    const float mv = maskV[grow];
    const float y0 = ((x0 - mean) * rstd * g0 + be0) * mv;
    const float y1 = ((x1 - mean) * rstd * g1 + be1) * mv;
    outV[(size_t)grow * 128 + lane]      = y0;
    outV[(size_t)grow * 128 + 64 + lane] = y1;
    Ts[row * 136 + lane]      = f2bf(y0);
    Ts[row * 136 + 64 + lane] = f2bf(y1);
  }
  __syncthreads();

  // fused k_pre for the edge pass: P1 = outV@W11top + b, P3 = outV@W11bot
  f32x4 a0[2] = {zf, zf}, a1[2] = {zf, zf};
  #pragma unroll
  for (int t = 0; t < 4; ++t) {
    const short8 a = *(const short8*)(&Ts[rr * 136 + t * 32 + kg]);
    #pragma unroll
    for (int c = 0; c < 2; ++c) {
      short8 bt = *(const short8*)(W11tp + ((size_t)(t * 8 + (w * 2 + c)) * 64 + lane) * 8);
      a0[c] = mfma16(a, bt, a0[c]);
      short8 bb = *(const short8*)(W11bp + ((size_t)(t * 8 + (w * 2 + c)) * 64 + lane) * 8);
      a1[c] = mfma16(a, bb, a1[c]);
    }
  }
  #pragma unroll
  for (int c = 0; c < 2; ++c) {
    const int col = w * 32 + c * 16 + rr;
    const float b = W11b[col];
    #pragma unroll
    for (int r = 0; r < 4; ++r) {
      const int row = row0 + ((lane >> 4) << 2) + r;
      P1[(size_t)row * 128 + col] = a0[c][r] + b;
      P3[(size_t)row * 128 + col] = f2bf(a1[c][r]);
    }
  }
}

// ---------------- edge update + LN3 -> outE (load-all staging + fence) -------
template<bool HEB>
__global__ __launch_bounds__(256) void k_edge_t(
    const float* __restrict__ hE, const unsigned short* __restrict__ hEb,
    const int* __restrict__ Eidx,
    const float* __restrict__ P1g, const unsigned short* __restrict__ P3g,
    const unsigned short* __restrict__ Wmidp,
    const unsigned short* __restrict__ W12p, const float* __restrict__ W12b,
    const unsigned short* __restrict__ W13p, const float* __restrict__ W13b,
    const float* __restrict__ ln3g, const float* __restrict__ ln3b,
    float* __restrict__ outE)
{
  __shared__ __align__(16) unsigned short Xs[48 * 136];   // hE bf16, later GEMM2-out
  __shared__ __align__(16) unsigned short Ms[48 * 136];   // P3 gather, later GEMM1-out
  __shared__ float sums[48 * 4];
  __shared__ float sqs[48 * 4];
  __shared__ float mr[96];

  const int tid = threadIdx.x;
  const int lane = tid & 63;
  const int w = tid >> 6;
  const int rr = lane & 15;
  const int g4 = (lane >> 4) << 2;
  const int bidx = (blockIdx.x & 7) * 512 + (blockIdx.x >> 3);   // XCD swizzle
  const int bbase = bidx & ~2047;

  const int* idxr = Eidx + (size_t)bidx * 48;

  // ---- staging: issue ALL loads, fence, then stores ----
  int jj[3];
  #pragma unroll
  for (int i = 0; i < 3; ++i) jj[i] = idxr[(tid + i * 256) >> 4];

  short8 tvb[3]; float4 tvf[6];
  if constexpr (HEB) {
    #pragma unroll
    for (int i = 0; i < 3; ++i) {
      const int e = tid + i * 256;
      tvb[i] = *(const short8*)(hEb + (size_t)bidx * 6144 + (e >> 4) * 128 + ((e & 15) << 3));
    }
  } else {
    #pragma unroll
    for (int i = 0; i < 6; ++i) {
      const int e = tid + i * 256;
      tvf[i] = *(const float4*)(hE + (size_t)bidx * 6144 + (e >> 5) * 128 + ((e & 31) << 2));
    }
  }
  short8 gv[3];
  #pragma unroll
  for (int i = 0; i < 3; ++i) {
    const int e = tid + i * 256;
    gv[i] = *(const short8*)(P3g + (size_t)(bbase + jj[i]) * 128 + ((e & 15) << 3));
  }
  __builtin_amdgcn_sched_barrier(0);   // loads above, consumers below
  const float p1c0 = P1g[(size_t)bidx * 128 + w * 32 + rr];
  const float p1c1 = P1g[(size_t)bidx * 128 + w * 32 + 16 + rr];

  if constexpr (HEB) {
    #pragma unroll
    for (int i = 0; i < 3; ++i) {
      const int e = tid + i * 256;
      *(short8*)(&Xs[(e >> 4) * 136 + ((e & 15) << 3)]) = tvb[i];
    }
  } else {
    #pragma unroll
    for (int i = 0; i < 6; ++i) {
      const int e = tid + i * 256, r = e >> 5, q = (e & 31) << 2;
      uint2 pk; pk.x = pk2(tvf[i].x, tvf[i].y); pk.y = pk2(tvf[i].z, tvf[i].w);
      *(uint2*)(&Xs[r * 136 + q]) = pk;
    }
  }
  #pragma unroll
  for (int i = 0; i < 3; ++i) {
    const int e = tid + i * 256;
    *(short8*)(&Ms[(e >> 4) * 136 + ((e & 15) << 3)]) = gv[i];
  }
  __syncthreads();                                        // B1

  // residual capture (wave-own cols) + acc-init
  f32x4 acc[3][2];
  float res[3][2][4];
  #pragma unroll
  for (int m = 0; m < 3; ++m)
    #pragma unroll
    for (int c = 0; c < 2; ++c)
      #pragma unroll
      for (int r = 0; r < 4; ++r) {
        const int row = m * 16 + g4 + r;
        const int col = w * 32 + c * 16 + rr;
        acc[m][c][r] = (c ? p1c1 : p1c0) + bf2f(Ms[row * 136 + col]);
        res[m][c][r] = bf2f(Xs[row * 136 + col]);
      }

  gemm_tiles<4, 3, 8>(Xs, 136, Wmidp, lane, w, acc);
  #pragma unroll
  for (int m = 0; m < 3; ++m)
    #pragma unroll
    for (int c = 0; c < 2; ++c)
      #pragma unroll
      for (int r = 0; r < 4; ++r) {
        const int row = m * 16 + g4 + r;
        Ms[row * 136 + w * 32 + c * 16 + rr] = f2bf(gelu_f(acc[m][c][r]));
      }
  __syncthreads();                                        // B2

  const f32x4 zf = {0.f, 0.f, 0.f, 0.f};
  #pragma unroll
  for (int m = 0; m < 3; ++m) { acc[m][0] = zf; acc[m][1] = zf; }
  gemm_tiles<4, 3, 8>(Ms, 136, W12p, lane, w, acc);
  {
    const float b0 = W12b[w * 32 + rr], b1 = W12b[w * 32 + 16 + rr];
    #pragma unroll
    for (int m = 0; m < 3; ++m)
      #pragma unroll
      for (int c = 0; c < 2; ++c)
        #pragma unroll
        for (int r = 0; r < 4; ++r) {
          const int row = m * 16 + g4 + r;
          Xs[row * 136 + w * 32 + c * 16 + rr] = f2bf(gelu_f(acc[m][c][r] + (c ? b1 : b0)));
        }
  }
  __syncthreads();                                        // B3

  #pragma unroll
  for (int m = 0; m < 3; ++m) { acc[m][0] = zf; acc[m][1] = zf; }
  gemm_tiles<4, 3, 8>(Xs, 136, W13p, lane, w, acc);

  {
    const float b0 = W13b[w * 32 + rr], b1 = W13b[w * 32 + 16 + rr];
    #pragma unroll
    for (int m = 0; m < 3; ++m)
      #pragma unroll
      for (int r = 0; r < 4; ++r) {
        const int row = m * 16 + g4 + r;
        acc[m][0][r] += b0 + res[m][0][r];
        acc[m][1][r] += b1 + res[m][1][r];
        float s = acc[m][0][r] + acc[m][1][r];
        float q2 = acc[m][0][r] * acc[m][0][r] + acc[m][1][r] * acc[m][1][r];
        s += __shfl_xor(s, 1); q2 += __shfl_xor(q2, 1);
        s += __shfl_xor(s, 2); q2 += __shfl_xor(q2, 2);
        s += __shfl_xor(s, 4); q2 += __shfl_xor(q2, 4);
        s += __shfl_xor(s, 8); q2 += __shfl_xor(q2, 8);
        if ((lane & 15) == 0) { sums[row * 4 + w] = s; sqs[row * 4 + w] = q2; }
      }
  }
  __syncthreads();                                        // B4
  if (tid < 48) {
    const float s = sums[tid * 4] + sums[tid * 4 + 1] + sums[tid * 4 + 2] + sums[tid * 4 + 3];
    const float q2 = sqs[tid * 4] + sqs[tid * 4 + 1] + sqs[tid * 4 + 2] + sqs[tid * 4 + 3];
    const float mean = s * (1.f / 128.f);
    mr[tid * 2] = mean;
    mr[tid * 2 + 1] = rsqrtf(q2 * (1.f / 128.f) - mean * mean + 1e-5f);
  }
  __syncthreads();                                        // B5
  {
    const float g0 = ln3g[w * 32 + rr], g1 = ln3g[w * 32 + 16 + rr];
    const float be0 = ln3b[w * 32 + rr], be1 = ln3b[w * 32 + 16 + rr];
    #pragma unroll
    for (int m = 0; m < 3; ++m)
      #pragma unroll
      for (int r = 0; r < 4; ++r) {
        const int row = m * 16 + g4 + r;
        const float mean = mr[row * 2], rstd = mr[row * 2 + 1];
        const size_t base = (size_t)bidx * 6144 + (size_t)row * 128 + w * 32 + rr;
        outE[base]      = (acc[m][0][r] - mean) * rstd * g0 + be0;
        outE[base + 16] = (acc[m][1][r] - mean) * rstd * g1 + be1;
      }
  }
}

extern "C" void kernel_launch(void* const* d_in, const int* in_sizes, int n_in,
                              void* d_out, int out_size, void* d_ws, size_t ws_size,
                              hipStream_t stream) {
  const float* hV    = (const float*)d_in[0];
  const float* hE    = (const float*)d_in[1];
  const int*   Eidx  = (const int*)d_in[2];
  const float* maskV = (const float*)d_in[3];
  const float* maskA = (const float*)d_in[4];
  const float* W1w  = (const float*)d_in[5];  const float* W1b  = (const float*)d_in[6];
  const float* W2w  = (const float*)d_in[7];  const float* W2b  = (const float*)d_in[8];
  const float* W3w  = (const float*)d_in[9];  const float* W3b  = (const float*)d_in[10];
  const float* W11w = (const float*)d_in[11]; const float* W11b = (const float*)d_in[12];
  const float* W12w = (const float*)d_in[13]; const float* W12b = (const float*)d_in[14];
  const float* W13w = (const float*)d_in[15]; const float* W13b = (const float*)d_in[16];
  const float* Winw = (const float*)d_in[17]; const float* Winb = (const float*)d_in[18];
  const float* Woutw= (const float*)d_in[19]; const float* Woutb= (const float*)d_in[20];
  const float* ln1g = (const float*)d_in[21]; const float* ln1b = (const float*)d_in[22];
  const float* ln2g = (const float*)d_in[23]; const float* ln2b = (const float*)d_in[24];
  const float* ln3g = (const float*)d_in[25]; const float* ln3b = (const float*)d_in[26];

  float* outV = (float*)d_out;                       // [4096,128]
  float* outE = outV + (size_t)4096 * 128;           // [4096*48,128]

  char* ws = (char*)d_ws;
  float* hVn1 = (float*)ws;                                  // 2 MB
  float* P1   = (float*)(ws + (size_t)2 * 1024 * 1024);      // 2 MB
  unsigned short* P3 = (unsigned short*)(ws + (size_t)4 * 1024 * 1024);  // 1 MB
  unsigned short* Wp = (unsigned short*)(ws + (size_t)5 * 1024 * 1024);  // 576 KB
  unsigned short* hEb = (unsigned short*)(ws + (size_t)6 * 1024 * 1024); // 48 MB bf16

  const size_t NEED = (size_t)6 * 1024 * 1024 + (size_t)4096 * 48 * 128 * 2;
  const bool heb = ws_size >= NEED;

  const unsigned short* W1top_p  = Wp;
  const unsigned short* W1mid_p  = Wp + (size_t)2048 * 8;
  const unsigned short* W1bot_p  = Wp + (size_t)4096 * 8;
  const unsigned short* W2p      = Wp + (size_t)6144 * 8;
  const unsigned short* W11top_p = Wp + (size_t)10240 * 8;
  const unsigned short* W11mid_p = Wp + (size_t)12288 * 8;
  const unsigned short* W11bot_p = Wp + (size_t)14336 * 8;
  const unsigned short* W12p     = Wp + (size_t)16384 * 8;
  const unsigned short* W13p     = Wp + (size_t)18432 * 8;
  const unsigned short* Winp     = Wp + (size_t)20480 * 8;
  const unsigned short* Woutp    = Wp + (size_t)28672 * 8;

  k_pack<<<144, 256, 0, stream>>>(W1w, W2w, W3w, W11w, W12w, W13w, Winw, Woutw, Wp);
  k_pre<<<256, 256, 0, stream>>>(hV, W1top_p, W1bot_p, W1b, P1, P3);

  if (heb)
    k_node_t<true><<<4096, 256, 0, stream>>>(hV, hE, hEb, Eidx, maskA, P1, P3,
                                             W1mid_p, W2p, W2b, W3w, W3b,
                                             ln1g, ln1b, hVn1);
  else
    k_node_t<false><<<4096, 256, 0, stream>>>(hV, hE, hEb, Eidx, maskA, P1, P3,
                                              W1mid_p, W2p, W2b, W3w, W3b,
                                              ln1g, ln1b, hVn1);

  k_ffn<<<256, 256, 0, stream>>>(hVn1, Winp, Winb, Woutp, Woutb,
                                 ln2g, ln2b, maskV,
                                 W11top_p, W11bot_p, W11b,
                                 outV, P1, P3);

  if (heb)
    k_edge_t<true><<<4096, 256, 0, stream>>>(hE, hEb, Eidx, P1, P3,
                                             W11mid_p, W12p, W12b, W13p, W13b,
                                             ln3g, ln3b, outE);
  else
    k_edge_t<false><<<4096, 256, 0, stream>>>(hE, hEb, Eidx, P1, P3,
                                              W11mid_p, W12p, W12b, W13p, W13b,
                                              ln3g, ln3b, outE);
}